// Round 8
// baseline (1599.030 us; speedup 1.0000x reference)
//
#include <hip/hip_runtime.h>

// LeNet-5 forward, fully fused, ONE WAVE PER IMAGE (64-thread blocks).
// ALL three convs on bf16 MFMA (16x16x32); only epilogues + fc on VALU.
//
// Round-8: explicit ring-2 register prefetch of weight fragments in the
// conv2/conv3 K-loops (hides ~200-400cyc L2 latency under MFMAs), and conv1
// regrouped to 2x6 nt-groups (halves xbf re-reads, 2x MFMAs per A-frag).
//
// Layouts (unchanged from round 7):
//   conv1 as GEMM (row-only im2col), banded weights K=288, N=192.
//   h1: bf16 19x248 ([x*12+c], pads zeroed)  -- stride 248 = conflict-free
//   h2: bf16 10x248 ([x*20+c], pads zeroed)
//   all K-padding baked into pre-packed weights (zeros).

typedef short s16x4 __attribute__((ext_vector_type(4)));
typedef short s16x8 __attribute__((ext_vector_type(8)));
typedef float f32x4 __attribute__((ext_vector_type(4)));

#define ROW1 248
#define ROW2 248
#define XOFF 4712           // xbf elem offset (= 19*248)
#define SM_BYTES 11024

static __device__ __forceinline__ unsigned short f2bf(float f) {
    union { float f; unsigned int u; } v; v.f = f;
    unsigned int u = v.u;
    unsigned int r = (u + 0x7fffu + ((u >> 16) & 1u)) >> 16;   // RNE
    return (unsigned short)r;
}

static __device__ __forceinline__ s16x8 cat8(s16x4 lo, s16x4 hi) {
    return __builtin_shufflevector(lo, hi, 0, 1, 2, 3, 4, 5, 6, 7);
}

// ---- weight prep ----------------------------------------------------------
// wbuf ushort: [0,40960) conv2 B-frags, [40960,61440) conv3 B-frags,
//              [61440,116736) conv1 banded B-frags (wband).
// All use the 16x16x32 B-frag convention: n = nt*16 + (lane&15),
// k = kc*32 + ((lane>>4)&3)*8 + t.
__global__ __launch_bounds__(256) void wprep_k(const float* __restrict__ w1,
                                               const float* __restrict__ w2,
                                               const float* __restrict__ w3,
                                               unsigned short* __restrict__ wbuf) {
    int e = blockIdx.x * 256 + threadIdx.x;
    if (e < 40960) {                       // conv2: j=k/12, c=k%12
        int t = e & 7, lane = (e >> 3) & 63, nt = (e >> 9) & 1;
        int ck = (e >> 10) & 3, i = e >> 12;
        int k = ck * 32 + ((lane >> 4) & 3) * 8 + t;
        int o = nt * 16 + (lane & 15);
        int j = k / 12, c = k % 12;
        float val = (j < 10 && c < 10 && o < 20) ? w2[o * 1000 + c * 100 + i * 10 + j] : 0.f;
        wbuf[e] = f2bf(val);
    } else if (e < 61440) {                // conv3: j=k/20, c=k%20
        int e2 = e - 40960;
        int t = e2 & 7, lane = (e2 >> 3) & 63, nt = (e2 >> 9) & 1;
        int ck = (e2 >> 10) & 3, i = e2 >> 12;
        int k = ck * 32 + ((lane >> 4) & 3) * 8 + t;
        int o = nt * 16 + (lane & 15);
        int j = k / 20, c = k % 20;
        float val = (j < 5 && o < 20) ? w3[o * 500 + c * 25 + i * 5 + j] : 0.f;
        wbuf[e] = f2bf(val);
    } else {                               // conv1 band: [nt(12)][kc(9)][lane][t]
        int e2 = e - 61440;                // < 55296
        int t = e2 & 7, lane = (e2 >> 3) & 63;
        int kc = (e2 >> 9) % 9, nt = (e2 >> 9) / 9;
        int n = nt * 16 + (lane & 15);
        int k = kc * 32 + ((lane >> 4) & 3) * 8 + t;
        float val = 0.f;
        if (n < 190 && k < 280) {
            int ox = n / 10, o = n - ox * 10;
            int i = k / 28, xc = k - i * 28;
            int j = xc - ox;
            if (j >= 0 && j < 10) val = w1[o * 100 + i * 10 + j];
        }
        wbuf[61440 + e2] = f2bf(val);
    }
}

// --------------------------- the fused kernel ------------------------------
__global__ __launch_bounds__(64, 4) void fused_k(const float* __restrict__ x,
                                                 const float* __restrict__ b1,
                                                 const unsigned short* __restrict__ wbuf2,
                                                 const unsigned short* __restrict__ wbuf3,
                                                 const unsigned short* __restrict__ wband,
                                                 const float* __restrict__ b2,
                                                 const float* __restrict__ b3,
                                                 const float* __restrict__ wf,
                                                 const float* __restrict__ bf,
                                                 float* __restrict__ out) {
    __shared__ __align__(16) unsigned char smem[SM_BYTES];
    unsigned short* sm16 = (unsigned short*)smem;
    unsigned short* h1  = sm16;                 // [0, 4712) elems
    unsigned short* xbf = sm16 + XOFF;          // [4712, 5512) elems
    unsigned short* h2s = sm16;                 // later: [0, 2480) elems
    float*          h3s = (float*)smem;         // later: [0, 720) floats

    const int lane = threadIdx.x;
    const int b = blockIdx.x;
    const int quad = lane >> 4, lm = lane & 15;

    // ---- phase 1: stage x as bf16; zero xbf tail, h1 row-pads & c-pads ----
    {
        const float4* src = (const float4*)(x + (size_t)b * 784);
        for (int k = lane; k < 196; k += 64) {
            float4 v = src[k];
            s16x4 p = { (short)f2bf(v.x), (short)f2bf(v.y),
                        (short)f2bf(v.z), (short)f2bf(v.w) };
            *(s16x4*)(xbf + k * 4) = p;
        }
        if (lane < 16) xbf[784 + lane] = 0;
        for (int e = lane; e < 95; e += 64) {          // row pads [228,248) x 19
            int row = e / 5, seg = e - row * 5;
            *(s16x4*)(h1 + row * ROW1 + 228 + seg * 4) = (s16x4){0, 0, 0, 0};
        }
        for (int e = lane; e < 361; e += 64) {         // c-pads (oy,ox,[10,12))
            int oy = e / 19, ox = e - oy * 19;
            *(unsigned int*)(h1 + oy * ROW1 + ox * 12 + 10) = 0u;
        }
    }
    __syncthreads();

    // ---- phase 2: conv1 MFMA  M=32(19), N=192(190), K=288(280) ----
    // 2 groups of 6 nt: each A-frag pair feeds 12 MFMAs.
    {
        int m1 = lm + 16; if (m1 > 18) m1 = 18;        // clamp pad rows
        const unsigned short* ab0 = xbf + lm * 28 + quad * 8;
        const unsigned short* ab1 = xbf + m1 * 28 + quad * 8;
        const unsigned short* wb = wband + lane * 8;
#pragma unroll 1
        for (int g = 0; g < 2; ++g) {
            f32x4 acc1[6][2] = {};
#pragma unroll
            for (int kc = 0; kc < 9; ++kc) {
                s16x8 a0 = cat8(*(const s16x4*)(ab0 + kc * 32),
                                *(const s16x4*)(ab0 + kc * 32 + 4));
                s16x8 a1 = cat8(*(const s16x4*)(ab1 + kc * 32),
                                *(const s16x4*)(ab1 + kc * 32 + 4));
#pragma unroll
                for (int q = 0; q < 6; ++q) {
                    int nt = g * 6 + q;
                    s16x8 bw = *(const s16x8*)(wb + (nt * 9 + kc) * 512);
                    acc1[q][0] = __builtin_amdgcn_mfma_f32_16x16x32_bf16(a0, bw, acc1[q][0], 0, 0, 0);
                    acc1[q][1] = __builtin_amdgcn_mfma_f32_16x16x32_bf16(a1, bw, acc1[q][1], 0, 0, 0);
                }
            }
#pragma unroll
            for (int q = 0; q < 6; ++q) {
                int n = (g * 6 + q) * 16 + lm;
                if (n < 190) {
                    int ox = n / 10, o = n - ox * 10;
                    float bias = b1[o];
#pragma unroll
                    for (int mt = 0; mt < 2; ++mt) {
#pragma unroll
                        for (int r = 0; r < 4; ++r) {
                            int oy = mt * 16 + quad * 4 + r;
                            if (oy < 19)
                                h1[oy * ROW1 + ox * 12 + o] =
                                    f2bf(fmaxf(acc1[q][mt][r] + bias, 0.f));
                        }
                    }
                }
            }
        }
    }
    __syncthreads();

    // ---- phase 3: conv2 MFMA  M=112(100), N=32(20), K=1280(1000) ----
    // Flattened it = i*4 + ck (40 steps); ring-2 distance-1 weight prefetch.
    int abase[7];
#pragma unroll
    for (int mt = 0; mt < 7; ++mt) {
        int m = mt * 16 + lm;
        if (m > 99) m = 99;
        int y = m / 10, xx = m - 10 * y;
        abase[mt] = y * ROW1 + xx * 12 + quad * 8;
    }
    f32x4 acc[7][2] = {};
    {
        const unsigned short* wptr = wbuf2 + lane * 8;
        s16x8 wq[2][2];
        wq[0][0] = *(const s16x8*)(wptr);
        wq[0][1] = *(const s16x8*)(wptr + 512);
#pragma unroll 1
        for (int it = 0; it < 40; ++it) {
            // prefetch next step's fragments (it=39 reads into conv3 region:
            // valid memory, value unused)
            int nx = it + 1;
            wq[nx & 1][0] = *(const s16x8*)(wptr + nx * 1024);
            wq[nx & 1][1] = *(const s16x8*)(wptr + nx * 1024 + 512);
            const unsigned short* sbi = h1 + (it >> 2) * ROW1 + (it & 3) * 32;
            s16x8 af[7];
#pragma unroll
            for (int mt = 0; mt < 7; ++mt) {
                const unsigned short* p = sbi + abase[mt];
                af[mt] = cat8(*(const s16x4*)(p), *(const s16x4*)(p + 4));
            }
            s16x8 w0 = wq[it & 1][0], w1 = wq[it & 1][1];
#pragma unroll
            for (int mt = 0; mt < 7; ++mt) {
                acc[mt][0] = __builtin_amdgcn_mfma_f32_16x16x32_bf16(af[mt], w0, acc[mt][0], 0, 0, 0);
                acc[mt][1] = __builtin_amdgcn_mfma_f32_16x16x32_bf16(af[mt], w1, acc[mt][1], 0, 0, 0);
            }
        }
    }
    __syncthreads();   // h1 fully consumed; region becomes h2s

    // ---- phase 4: zero h2 row-pads + scatter conv2 -> h2s ([x*20+c]) ----
    for (int e = lane; e < 120; e += 64) {             // pads [200,248) x 10
        int row = e / 12, seg = e - row * 12;
        *(s16x4*)(h2s + row * ROW2 + 200 + seg * 4) = (s16x4){0, 0, 0, 0};
    }
#pragma unroll
    for (int nt = 0; nt < 2; ++nt) {
        int o = nt * 16 + lm;
        if (o < 20) {
            float bias = b2[o];
#pragma unroll
            for (int mt = 0; mt < 7; ++mt) {
#pragma unroll
                for (int r = 0; r < 4; ++r) {
                    int pos = mt * 16 + quad * 4 + r;
                    if (pos < 100) {
                        int y2 = pos / 10, x2 = pos - 10 * y2;
                        h2s[y2 * ROW2 + x2 * 20 + o] = f2bf(fmaxf(acc[mt][nt][r] + bias, 0.f));
                    }
                }
            }
        }
    }
    __syncthreads();

    // ---- phase 5: conv3 MFMA  M=48(36), N=32(20), K=640(500) ----
    // Flattened it = i*4 + ck (20 steps); ring-2 distance-1 weight prefetch.
    int abase3[3];
#pragma unroll
    for (int mt = 0; mt < 3; ++mt) {
        int m = mt * 16 + lm;
        if (m > 35) m = 35;
        int oy = m / 6, ox = m - 6 * oy;
        abase3[mt] = oy * ROW2 + ox * 20 + quad * 8;
    }
    f32x4 acc3[3][2] = {};
    {
        const unsigned short* wptr = wbuf3 + lane * 8;
        s16x8 wq[2][2];
        wq[0][0] = *(const s16x8*)(wptr);
        wq[0][1] = *(const s16x8*)(wptr + 512);
#pragma unroll 1
        for (int it = 0; it < 20; ++it) {
            int nx = it + 1;                 // it=19 reads into wband: unused
            wq[nx & 1][0] = *(const s16x8*)(wptr + nx * 1024);
            wq[nx & 1][1] = *(const s16x8*)(wptr + nx * 1024 + 512);
            const unsigned short* sbi = h2s + (it >> 2) * ROW2 + (it & 3) * 32;
            s16x8 af[3];
#pragma unroll
            for (int mt = 0; mt < 3; ++mt) {
                const unsigned short* p = sbi + abase3[mt];
                af[mt] = cat8(*(const s16x4*)(p), *(const s16x4*)(p + 4));
            }
            s16x8 w0 = wq[it & 1][0], w1 = wq[it & 1][1];
#pragma unroll
            for (int mt = 0; mt < 3; ++mt) {
                acc3[mt][0] = __builtin_amdgcn_mfma_f32_16x16x32_bf16(af[mt], w0, acc3[mt][0], 0, 0, 0);
                acc3[mt][1] = __builtin_amdgcn_mfma_f32_16x16x32_bf16(af[mt], w1, acc3[mt][1], 0, 0, 0);
            }
        }
    }
    __syncthreads();   // h2s consumed; region becomes h3s

    // ---- phase 6: conv3 epilogue -> linear h3s[o*36+pos] (fp32, relu) ----
#pragma unroll
    for (int nt = 0; nt < 2; ++nt) {
        int o = nt * 16 + lm;
        if (o < 20) {
            float b3v = b3[o];
#pragma unroll
            for (int mt = 0; mt < 3; ++mt) {
#pragma unroll
                for (int r = 0; r < 4; ++r) {
                    int pos = mt * 16 + quad * 4 + r;
                    if (pos < 36)
                        h3s[o * 36 + pos] = fmaxf(acc3[mt][nt][r] + b3v, 0.f);
                }
            }
        }
    }
    __syncthreads();

    // ---- phase 7: fc — coalesced global wf, lane l handles k=l+64s ----
    float part[10];
#pragma unroll
    for (int n = 0; n < 10; ++n) part[n] = 0.f;
#pragma unroll 1
    for (int s = 0; s < 12; ++s) {
        int k = s * 64 + lane;
        if (k < 720) {
            float v = h3s[k];
#pragma unroll
            for (int n = 0; n < 10; ++n)
                part[n] = fmaf(v, wf[n * 720 + k], part[n]);
        }
    }
#pragma unroll
    for (int n = 0; n < 10; ++n) {
#pragma unroll
        for (int off = 32; off >= 1; off >>= 1)
            part[n] += __shfl_xor(part[n], off, 64);
    }
    if (lane == 0) {
        float* op = out + (size_t)b * 10;
#pragma unroll
        for (int n = 0; n < 10; ++n) op[n] = part[n] + bf[n];
    }
}

extern "C" void kernel_launch(void* const* d_in, const int* in_sizes, int n_in,
                              void* d_out, int out_size, void* d_ws, size_t ws_size,
                              hipStream_t stream) {
    (void)n_in; (void)out_size; (void)ws_size;
    const float* x  = (const float*)d_in[0];
    const float* w1 = (const float*)d_in[1];
    const float* b1 = (const float*)d_in[2];
    const float* w2 = (const float*)d_in[3];
    const float* b2 = (const float*)d_in[4];
    const float* w3 = (const float*)d_in[5];
    const float* b3 = (const float*)d_in[6];
    const float* wf = (const float*)d_in[7];
    const float* bf = (const float*)d_in[8];
    float* out = (float*)d_out;

    const int B = in_sizes[0] / 784;                   // 4096

    unsigned short* wbuf = (unsigned short*)d_ws;      // 116736 bf16 = 228 KB

    wprep_k<<<456, 256, 0, stream>>>(w1, w2, w3, wbuf);
    fused_k<<<B, 64, 0, stream>>>(x, b1, wbuf, wbuf + 40960, wbuf + 61440,
                                  b2, b3, wf, bf, out);
}

// Round 9
// 171.535 us; speedup vs baseline: 9.3219x; 9.3219x over previous
//
#include <hip/hip_runtime.h>

// LeNet-5 forward, fully fused, ONE WAVE PER IMAGE (64-thread blocks).
// ALL three convs on bf16 MFMA (16x16x32); only epilogues + fc on VALU.
//
// Round-9: round-7 body + compile-time software pipeline. conv2/conv3 K-loops
// are FULLY UNROLLED with a distance-1 weight prefetch held in NAMED vars
// (pure SSA renames under unroll -> guaranteed registers, no scratch).
// Round-8's runtime-indexed ring buffer spilled to scratch (24 MB WRITE_SIZE)
// and cost 17x -- never index prefetch state with runtime values.
//
// Layouts (unchanged from round 7):
//   conv1 as GEMM (row-only im2col), banded weights K=288, N=192.
//   h1: bf16 19x248 ([x*12+c], pads zeroed)  -- stride 248 = conflict-free
//   h2: bf16 10x248 ([x*20+c], pads zeroed)
//   all K-padding baked into pre-packed weights (zeros).

typedef short s16x4 __attribute__((ext_vector_type(4)));
typedef short s16x8 __attribute__((ext_vector_type(8)));
typedef float f32x4 __attribute__((ext_vector_type(4)));

#define ROW1 248
#define ROW2 248
#define XOFF 4712           // xbf elem offset (= 19*248)
#define SM_BYTES 11024

static __device__ __forceinline__ unsigned short f2bf(float f) {
    union { float f; unsigned int u; } v; v.f = f;
    unsigned int u = v.u;
    unsigned int r = (u + 0x7fffu + ((u >> 16) & 1u)) >> 16;   // RNE
    return (unsigned short)r;
}

static __device__ __forceinline__ s16x8 cat8(s16x4 lo, s16x4 hi) {
    return __builtin_shufflevector(lo, hi, 0, 1, 2, 3, 4, 5, 6, 7);
}

// ---- weight prep ----------------------------------------------------------
// wbuf ushort: [0,40960) conv2 B-frags, [40960,61440) conv3 B-frags,
//              [61440,116736) conv1 banded B-frags (wband).
// All use the 16x16x32 B-frag convention: n = nt*16 + (lane&15),
// k = kc*32 + ((lane>>4)&3)*8 + t.
__global__ __launch_bounds__(256) void wprep_k(const float* __restrict__ w1,
                                               const float* __restrict__ w2,
                                               const float* __restrict__ w3,
                                               unsigned short* __restrict__ wbuf) {
    int e = blockIdx.x * 256 + threadIdx.x;
    if (e < 40960) {                       // conv2: j=k/12, c=k%12
        int t = e & 7, lane = (e >> 3) & 63, nt = (e >> 9) & 1;
        int ck = (e >> 10) & 3, i = e >> 12;
        int k = ck * 32 + ((lane >> 4) & 3) * 8 + t;
        int o = nt * 16 + (lane & 15);
        int j = k / 12, c = k % 12;
        float val = (j < 10 && c < 10 && o < 20) ? w2[o * 1000 + c * 100 + i * 10 + j] : 0.f;
        wbuf[e] = f2bf(val);
    } else if (e < 61440) {                // conv3: j=k/20, c=k%20
        int e2 = e - 40960;
        int t = e2 & 7, lane = (e2 >> 3) & 63, nt = (e2 >> 9) & 1;
        int ck = (e2 >> 10) & 3, i = e2 >> 12;
        int k = ck * 32 + ((lane >> 4) & 3) * 8 + t;
        int o = nt * 16 + (lane & 15);
        int j = k / 20, c = k % 20;
        float val = (j < 5 && o < 20) ? w3[o * 500 + c * 25 + i * 5 + j] : 0.f;
        wbuf[e] = f2bf(val);
    } else {                               // conv1 band: [nt(12)][kc(9)][lane][t]
        int e2 = e - 61440;                // < 55296
        int t = e2 & 7, lane = (e2 >> 3) & 63;
        int kc = (e2 >> 9) % 9, nt = (e2 >> 9) / 9;
        int n = nt * 16 + (lane & 15);
        int k = kc * 32 + ((lane >> 4) & 3) * 8 + t;
        float val = 0.f;
        if (n < 190 && k < 280) {
            int ox = n / 10, o = n - ox * 10;
            int i = k / 28, xc = k - i * 28;
            int j = xc - ox;
            if (j >= 0 && j < 10) val = w1[o * 100 + i * 10 + j];
        }
        wbuf[61440 + e2] = f2bf(val);
    }
}

// --------------------------- the fused kernel ------------------------------
__global__ __launch_bounds__(64, 4) void fused_k(const float* __restrict__ x,
                                                 const float* __restrict__ b1,
                                                 const unsigned short* __restrict__ wbuf2,
                                                 const unsigned short* __restrict__ wbuf3,
                                                 const unsigned short* __restrict__ wband,
                                                 const float* __restrict__ b2,
                                                 const float* __restrict__ b3,
                                                 const float* __restrict__ wf,
                                                 const float* __restrict__ bf,
                                                 float* __restrict__ out) {
    __shared__ __align__(16) unsigned char smem[SM_BYTES];
    unsigned short* sm16 = (unsigned short*)smem;
    unsigned short* h1  = sm16;                 // [0, 4712) elems
    unsigned short* xbf = sm16 + XOFF;          // [4712, 5512) elems
    unsigned short* h2s = sm16;                 // later: [0, 2480) elems
    float*          h3s = (float*)smem;         // later: [0, 720) floats

    const int lane = threadIdx.x;
    const int b = blockIdx.x;
    const int quad = lane >> 4, lm = lane & 15;

    // ---- phase 1: stage x as bf16; zero xbf tail, h1 row-pads & c-pads ----
    {
        const float4* src = (const float4*)(x + (size_t)b * 784);
        for (int k = lane; k < 196; k += 64) {
            float4 v = src[k];
            s16x4 p = { (short)f2bf(v.x), (short)f2bf(v.y),
                        (short)f2bf(v.z), (short)f2bf(v.w) };
            *(s16x4*)(xbf + k * 4) = p;
        }
        if (lane < 16) xbf[784 + lane] = 0;
        for (int e = lane; e < 95; e += 64) {          // row pads [228,248) x 19
            int row = e / 5, seg = e - row * 5;
            *(s16x4*)(h1 + row * ROW1 + 228 + seg * 4) = (s16x4){0, 0, 0, 0};
        }
        for (int e = lane; e < 361; e += 64) {         // c-pads (oy,ox,[10,12))
            int oy = e / 19, ox = e - oy * 19;
            *(unsigned int*)(h1 + oy * ROW1 + ox * 12 + 10) = 0u;
        }
    }
    __syncthreads();

    // ---- phase 2: conv1 MFMA  M=32(19), N=192(190), K=288(280) ----
    // 2 groups of 6 nt: each A-frag pair feeds 12 MFMAs.
    {
        int m1 = lm + 16; if (m1 > 18) m1 = 18;        // clamp pad rows
        const unsigned short* ab0 = xbf + lm * 28 + quad * 8;
        const unsigned short* ab1 = xbf + m1 * 28 + quad * 8;
        const unsigned short* wb = wband + lane * 8;
#pragma unroll 1
        for (int g = 0; g < 2; ++g) {
            f32x4 acc1[6][2] = {};
#pragma unroll
            for (int kc = 0; kc < 9; ++kc) {
                s16x8 a0 = cat8(*(const s16x4*)(ab0 + kc * 32),
                                *(const s16x4*)(ab0 + kc * 32 + 4));
                s16x8 a1 = cat8(*(const s16x4*)(ab1 + kc * 32),
                                *(const s16x4*)(ab1 + kc * 32 + 4));
#pragma unroll
                for (int q = 0; q < 6; ++q) {
                    int nt = g * 6 + q;
                    s16x8 bw = *(const s16x8*)(wb + (nt * 9 + kc) * 512);
                    acc1[q][0] = __builtin_amdgcn_mfma_f32_16x16x32_bf16(a0, bw, acc1[q][0], 0, 0, 0);
                    acc1[q][1] = __builtin_amdgcn_mfma_f32_16x16x32_bf16(a1, bw, acc1[q][1], 0, 0, 0);
                }
            }
#pragma unroll
            for (int q = 0; q < 6; ++q) {
                int n = (g * 6 + q) * 16 + lm;
                if (n < 190) {
                    int ox = n / 10, o = n - ox * 10;
                    float bias = b1[o];
#pragma unroll
                    for (int mt = 0; mt < 2; ++mt) {
#pragma unroll
                        for (int r = 0; r < 4; ++r) {
                            int oy = mt * 16 + quad * 4 + r;
                            if (oy < 19)
                                h1[oy * ROW1 + ox * 12 + o] =
                                    f2bf(fmaxf(acc1[q][mt][r] + bias, 0.f));
                        }
                    }
                }
            }
        }
    }
    __syncthreads();

    // ---- phase 3: conv2 MFMA  M=112(100), N=32(20), K=1280(1000) ----
    // Fully unrolled 40 steps; distance-1 prefetch in NAMED vars (SSA).
    int abase[7];
#pragma unroll
    for (int mt = 0; mt < 7; ++mt) {
        int m = mt * 16 + lm;
        if (m > 99) m = 99;
        int y = m / 10, xx = m - 10 * y;
        abase[mt] = y * ROW1 + xx * 12 + quad * 8;
    }
    f32x4 acc[7][2] = {};
    {
        const unsigned short* wptr = wbuf2 + lane * 8;
        s16x8 wc0 = *(const s16x8*)(wptr);
        s16x8 wc1 = *(const s16x8*)(wptr + 512);
#pragma unroll
        for (int it = 0; it < 40; ++it) {
            // prefetch next step (it=39 reads into conv3 region: valid, unused)
            s16x8 wn0 = *(const s16x8*)(wptr + (it + 1) * 1024);
            s16x8 wn1 = *(const s16x8*)(wptr + (it + 1) * 1024 + 512);
            const unsigned short* sbi = h1 + (it >> 2) * ROW1 + (it & 3) * 32;
            s16x8 af[7];
#pragma unroll
            for (int mt = 0; mt < 7; ++mt) {
                const unsigned short* p = sbi + abase[mt];
                af[mt] = cat8(*(const s16x4*)(p), *(const s16x4*)(p + 4));
            }
#pragma unroll
            for (int mt = 0; mt < 7; ++mt) {
                acc[mt][0] = __builtin_amdgcn_mfma_f32_16x16x32_bf16(af[mt], wc0, acc[mt][0], 0, 0, 0);
                acc[mt][1] = __builtin_amdgcn_mfma_f32_16x16x32_bf16(af[mt], wc1, acc[mt][1], 0, 0, 0);
            }
            wc0 = wn0; wc1 = wn1;
        }
    }
    __syncthreads();   // h1 fully consumed; region becomes h2s

    // ---- phase 4: zero h2 row-pads + scatter conv2 -> h2s ([x*20+c]) ----
    for (int e = lane; e < 120; e += 64) {             // pads [200,248) x 10
        int row = e / 12, seg = e - row * 12;
        *(s16x4*)(h2s + row * ROW2 + 200 + seg * 4) = (s16x4){0, 0, 0, 0};
    }
#pragma unroll
    for (int nt = 0; nt < 2; ++nt) {
        int o = nt * 16 + lm;
        if (o < 20) {
            float bias = b2[o];
#pragma unroll
            for (int mt = 0; mt < 7; ++mt) {
#pragma unroll
                for (int r = 0; r < 4; ++r) {
                    int pos = mt * 16 + quad * 4 + r;
                    if (pos < 100) {
                        int y2 = pos / 10, x2 = pos - 10 * y2;
                        h2s[y2 * ROW2 + x2 * 20 + o] = f2bf(fmaxf(acc[mt][nt][r] + bias, 0.f));
                    }
                }
            }
        }
    }
    __syncthreads();

    // ---- phase 5: conv3 MFMA  M=48(36), N=32(20), K=640(500) ----
    // Fully unrolled 20 steps; distance-1 prefetch in NAMED vars.
    int abase3[3];
#pragma unroll
    for (int mt = 0; mt < 3; ++mt) {
        int m = mt * 16 + lm;
        if (m > 35) m = 35;
        int oy = m / 6, ox = m - 6 * oy;
        abase3[mt] = oy * ROW2 + ox * 20 + quad * 8;
    }
    f32x4 acc3[3][2] = {};
    {
        const unsigned short* wptr = wbuf3 + lane * 8;
        s16x8 wc0 = *(const s16x8*)(wptr);
        s16x8 wc1 = *(const s16x8*)(wptr + 512);
#pragma unroll
        for (int it = 0; it < 20; ++it) {
            s16x8 wn0 = *(const s16x8*)(wptr + (it + 1) * 1024);   // it=19 -> wband
            s16x8 wn1 = *(const s16x8*)(wptr + (it + 1) * 1024 + 512);
            const unsigned short* sbi = h2s + (it >> 2) * ROW2 + (it & 3) * 32;
            s16x8 af[3];
#pragma unroll
            for (int mt = 0; mt < 3; ++mt) {
                const unsigned short* p = sbi + abase3[mt];
                af[mt] = cat8(*(const s16x4*)(p), *(const s16x4*)(p + 4));
            }
#pragma unroll
            for (int mt = 0; mt < 3; ++mt) {
                acc3[mt][0] = __builtin_amdgcn_mfma_f32_16x16x32_bf16(af[mt], wc0, acc3[mt][0], 0, 0, 0);
                acc3[mt][1] = __builtin_amdgcn_mfma_f32_16x16x32_bf16(af[mt], wc1, acc3[mt][1], 0, 0, 0);
            }
            wc0 = wn0; wc1 = wn1;
        }
    }
    __syncthreads();   // h2s consumed; region becomes h3s

    // ---- phase 6: conv3 epilogue -> linear h3s[o*36+pos] (fp32, relu) ----
#pragma unroll
    for (int nt = 0; nt < 2; ++nt) {
        int o = nt * 16 + lm;
        if (o < 20) {
            float b3v = b3[o];
#pragma unroll
            for (int mt = 0; mt < 3; ++mt) {
#pragma unroll
                for (int r = 0; r < 4; ++r) {
                    int pos = mt * 16 + quad * 4 + r;
                    if (pos < 36)
                        h3s[o * 36 + pos] = fmaxf(acc3[mt][nt][r] + b3v, 0.f);
                }
            }
        }
    }
    __syncthreads();

    // ---- phase 7: fc — coalesced global wf, lane l handles k=l+64s ----
    float part[10];
#pragma unroll
    for (int n = 0; n < 10; ++n) part[n] = 0.f;
#pragma unroll 1
    for (int s = 0; s < 12; ++s) {
        int k = s * 64 + lane;
        if (k < 720) {
            float v = h3s[k];
#pragma unroll
            for (int n = 0; n < 10; ++n)
                part[n] = fmaf(v, wf[n * 720 + k], part[n]);
        }
    }
#pragma unroll
    for (int n = 0; n < 10; ++n) {
#pragma unroll
        for (int off = 32; off >= 1; off >>= 1)
            part[n] += __shfl_xor(part[n], off, 64);
    }
    if (lane == 0) {
        float* op = out + (size_t)b * 10;
#pragma unroll
        for (int n = 0; n < 10; ++n) op[n] = part[n] + bf[n];
    }
}

extern "C" void kernel_launch(void* const* d_in, const int* in_sizes, int n_in,
                              void* d_out, int out_size, void* d_ws, size_t ws_size,
                              hipStream_t stream) {
    (void)n_in; (void)out_size; (void)ws_size;
    const float* x  = (const float*)d_in[0];
    const float* w1 = (const float*)d_in[1];
    const float* b1 = (const float*)d_in[2];
    const float* w2 = (const float*)d_in[3];
    const float* b2 = (const float*)d_in[4];
    const float* w3 = (const float*)d_in[5];
    const float* b3 = (const float*)d_in[6];
    const float* wf = (const float*)d_in[7];
    const float* bf = (const float*)d_in[8];
    float* out = (float*)d_out;

    const int B = in_sizes[0] / 784;                   // 4096

    unsigned short* wbuf = (unsigned short*)d_ws;      // 116736 bf16 = 228 KB

    wprep_k<<<456, 256, 0, stream>>>(w1, w2, w3, wbuf);
    fused_k<<<B, 64, 0, stream>>>(x, b1, wbuf, wbuf + 40960, wbuf + 61440,
                                  b2, b3, wf, bf, out);
}

// Round 10
// 156.930 us; speedup vs baseline: 10.1894x; 1.0931x over previous
//
#include <hip/hip_runtime.h>

// LeNet-5 forward, fully fused, ONE WAVE PER IMAGE (64-thread blocks).
// ALL three convs on bf16 MFMA (16x16x32); only epilogues + fc on VALU.
//
// Round-10: (a) __launch_bounds__(64,3) -> 170-VGPR cap so the distance-1
// weight prefetch (named SSA vars, fully unrolled loops) fits WITHOUT spill
// (round 9 spilled at the 128 cap: WRITE_SIZE 4.7MB); occupancy is LDS-bound
// at ~14 blocks/CU so the cap change costs nothing. (b) single-wave blocks
// don't need __syncthreads: replaced with s_waitcnt lgkmcnt(0) + compiler
// memory fence -- cross-lane LDS RAW is safe (lockstep wave, DS ops retired),
// and NOT draining vmcnt lets weight prefetches survive phase boundaries.
//
// Layouts (unchanged from round 7):
//   conv1 as GEMM (row-only im2col), banded weights K=288, N=192.
//   h1: bf16 19x248 ([x*12+c], pads zeroed)  -- stride 248 = conflict-free
//   h2: bf16 10x248 ([x*20+c], pads zeroed)
//   all K-padding baked into pre-packed weights (zeros).

typedef short s16x4 __attribute__((ext_vector_type(4)));
typedef short s16x8 __attribute__((ext_vector_type(8)));
typedef float f32x4 __attribute__((ext_vector_type(4)));

#define ROW1 248
#define ROW2 248
#define XOFF 4712           // xbf elem offset (= 19*248)
#define SM_BYTES 11024

static __device__ __forceinline__ unsigned short f2bf(float f) {
    union { float f; unsigned int u; } v; v.f = f;
    unsigned int u = v.u;
    unsigned int r = (u + 0x7fffu + ((u >> 16) & 1u)) >> 16;   // RNE
    return (unsigned short)r;
}

static __device__ __forceinline__ s16x8 cat8(s16x4 lo, s16x4 hi) {
    return __builtin_shufflevector(lo, hi, 0, 1, 2, 3, 4, 5, 6, 7);
}

// Wave-level LDS fence for single-wave workgroups: all prior DS ops retired
// + compiler may not reorder memory ops across it. No vmcnt drain.
static __device__ __forceinline__ void wave_lds_fence() {
    asm volatile("s_waitcnt lgkmcnt(0)" ::: "memory");
}

// ---- weight prep ----------------------------------------------------------
// wbuf ushort: [0,40960) conv2 B-frags, [40960,61440) conv3 B-frags,
//              [61440,116736) conv1 banded B-frags (wband).
// All use the 16x16x32 B-frag convention: n = nt*16 + (lane&15),
// k = kc*32 + ((lane>>4)&3)*8 + t.
__global__ __launch_bounds__(256) void wprep_k(const float* __restrict__ w1,
                                               const float* __restrict__ w2,
                                               const float* __restrict__ w3,
                                               unsigned short* __restrict__ wbuf) {
    int e = blockIdx.x * 256 + threadIdx.x;
    if (e < 40960) {                       // conv2: j=k/12, c=k%12
        int t = e & 7, lane = (e >> 3) & 63, nt = (e >> 9) & 1;
        int ck = (e >> 10) & 3, i = e >> 12;
        int k = ck * 32 + ((lane >> 4) & 3) * 8 + t;
        int o = nt * 16 + (lane & 15);
        int j = k / 12, c = k % 12;
        float val = (j < 10 && c < 10 && o < 20) ? w2[o * 1000 + c * 100 + i * 10 + j] : 0.f;
        wbuf[e] = f2bf(val);
    } else if (e < 61440) {                // conv3: j=k/20, c=k%20
        int e2 = e - 40960;
        int t = e2 & 7, lane = (e2 >> 3) & 63, nt = (e2 >> 9) & 1;
        int ck = (e2 >> 10) & 3, i = e2 >> 12;
        int k = ck * 32 + ((lane >> 4) & 3) * 8 + t;
        int o = nt * 16 + (lane & 15);
        int j = k / 20, c = k % 20;
        float val = (j < 5 && o < 20) ? w3[o * 500 + c * 25 + i * 5 + j] : 0.f;
        wbuf[e] = f2bf(val);
    } else {                               // conv1 band: [nt(12)][kc(9)][lane][t]
        int e2 = e - 61440;                // < 55296
        int t = e2 & 7, lane = (e2 >> 3) & 63;
        int kc = (e2 >> 9) % 9, nt = (e2 >> 9) / 9;
        int n = nt * 16 + (lane & 15);
        int k = kc * 32 + ((lane >> 4) & 3) * 8 + t;
        float val = 0.f;
        if (n < 190 && k < 280) {
            int ox = n / 10, o = n - ox * 10;
            int i = k / 28, xc = k - i * 28;
            int j = xc - ox;
            if (j >= 0 && j < 10) val = w1[o * 100 + i * 10 + j];
        }
        wbuf[61440 + e2] = f2bf(val);
    }
}

// --------------------------- the fused kernel ------------------------------
__global__ __launch_bounds__(64, 3) void fused_k(const float* __restrict__ x,
                                                 const float* __restrict__ b1,
                                                 const unsigned short* __restrict__ wbuf2,
                                                 const unsigned short* __restrict__ wbuf3,
                                                 const unsigned short* __restrict__ wband,
                                                 const float* __restrict__ b2,
                                                 const float* __restrict__ b3,
                                                 const float* __restrict__ wf,
                                                 const float* __restrict__ bf,
                                                 float* __restrict__ out) {
    __shared__ __align__(16) unsigned char smem[SM_BYTES];
    unsigned short* sm16 = (unsigned short*)smem;
    unsigned short* h1  = sm16;                 // [0, 4712) elems
    unsigned short* xbf = sm16 + XOFF;          // [4712, 5512) elems
    unsigned short* h2s = sm16;                 // later: [0, 2480) elems
    float*          h3s = (float*)smem;         // later: [0, 720) floats

    const int lane = threadIdx.x;
    const int b = blockIdx.x;
    const int quad = lane >> 4, lm = lane & 15;

    // ---- phase 1: stage x as bf16; zero xbf tail, h1 row-pads & c-pads ----
    {
        const float4* src = (const float4*)(x + (size_t)b * 784);
        for (int k = lane; k < 196; k += 64) {
            float4 v = src[k];
            s16x4 p = { (short)f2bf(v.x), (short)f2bf(v.y),
                        (short)f2bf(v.z), (short)f2bf(v.w) };
            *(s16x4*)(xbf + k * 4) = p;
        }
        if (lane < 16) xbf[784 + lane] = 0;
        for (int e = lane; e < 95; e += 64) {          // row pads [228,248) x 19
            int row = e / 5, seg = e - row * 5;
            *(s16x4*)(h1 + row * ROW1 + 228 + seg * 4) = (s16x4){0, 0, 0, 0};
        }
        for (int e = lane; e < 361; e += 64) {         // c-pads (oy,ox,[10,12))
            int oy = e / 19, ox = e - oy * 19;
            *(unsigned int*)(h1 + oy * ROW1 + ox * 12 + 10) = 0u;
        }
    }
    wave_lds_fence();

    // ---- phase 2: conv1 MFMA  M=32(19), N=192(190), K=288(280) ----
    // 2 groups of 6 nt: each A-frag pair feeds 12 MFMAs.
    {
        int m1 = lm + 16; if (m1 > 18) m1 = 18;        // clamp pad rows
        const unsigned short* ab0 = xbf + lm * 28 + quad * 8;
        const unsigned short* ab1 = xbf + m1 * 28 + quad * 8;
        const unsigned short* wb = wband + lane * 8;
#pragma unroll 1
        for (int g = 0; g < 2; ++g) {
            f32x4 acc1[6][2] = {};
#pragma unroll
            for (int kc = 0; kc < 9; ++kc) {
                s16x8 a0 = cat8(*(const s16x4*)(ab0 + kc * 32),
                                *(const s16x4*)(ab0 + kc * 32 + 4));
                s16x8 a1 = cat8(*(const s16x4*)(ab1 + kc * 32),
                                *(const s16x4*)(ab1 + kc * 32 + 4));
#pragma unroll
                for (int q = 0; q < 6; ++q) {
                    int nt = g * 6 + q;
                    s16x8 bw = *(const s16x8*)(wb + (nt * 9 + kc) * 512);
                    acc1[q][0] = __builtin_amdgcn_mfma_f32_16x16x32_bf16(a0, bw, acc1[q][0], 0, 0, 0);
                    acc1[q][1] = __builtin_amdgcn_mfma_f32_16x16x32_bf16(a1, bw, acc1[q][1], 0, 0, 0);
                }
            }
#pragma unroll
            for (int q = 0; q < 6; ++q) {
                int n = (g * 6 + q) * 16 + lm;
                if (n < 190) {
                    int ox = n / 10, o = n - ox * 10;
                    float bias = b1[o];
#pragma unroll
                    for (int mt = 0; mt < 2; ++mt) {
#pragma unroll
                        for (int r = 0; r < 4; ++r) {
                            int oy = mt * 16 + quad * 4 + r;
                            if (oy < 19)
                                h1[oy * ROW1 + ox * 12 + o] =
                                    f2bf(fmaxf(acc1[q][mt][r] + bias, 0.f));
                        }
                    }
                }
            }
        }
    }
    wave_lds_fence();

    // ---- phase 3: conv2 MFMA  M=112(100), N=32(20), K=1280(1000) ----
    // Fully unrolled 40 steps; distance-1 prefetch in NAMED vars (SSA).
    int abase[7];
#pragma unroll
    for (int mt = 0; mt < 7; ++mt) {
        int m = mt * 16 + lm;
        if (m > 99) m = 99;
        int y = m / 10, xx = m - 10 * y;
        abase[mt] = y * ROW1 + xx * 12 + quad * 8;
    }
    f32x4 acc[7][2] = {};
    {
        const unsigned short* wptr = wbuf2 + lane * 8;
        s16x8 wc0 = *(const s16x8*)(wptr);
        s16x8 wc1 = *(const s16x8*)(wptr + 512);
#pragma unroll
        for (int it = 0; it < 40; ++it) {
            // prefetch next step (it=39 reads into conv3 region: valid, unused)
            s16x8 wn0 = *(const s16x8*)(wptr + (it + 1) * 1024);
            s16x8 wn1 = *(const s16x8*)(wptr + (it + 1) * 1024 + 512);
            const unsigned short* sbi = h1 + (it >> 2) * ROW1 + (it & 3) * 32;
            s16x8 af[7];
#pragma unroll
            for (int mt = 0; mt < 7; ++mt) {
                const unsigned short* p = sbi + abase[mt];
                af[mt] = cat8(*(const s16x4*)(p), *(const s16x4*)(p + 4));
            }
#pragma unroll
            for (int mt = 0; mt < 7; ++mt) {
                acc[mt][0] = __builtin_amdgcn_mfma_f32_16x16x32_bf16(af[mt], wc0, acc[mt][0], 0, 0, 0);
                acc[mt][1] = __builtin_amdgcn_mfma_f32_16x16x32_bf16(af[mt], wc1, acc[mt][1], 0, 0, 0);
            }
            wc0 = wn0; wc1 = wn1;
        }
    }
    wave_lds_fence();   // h1 fully consumed; region becomes h2s

    // ---- phase 4: zero h2 row-pads + scatter conv2 -> h2s ([x*20+c]) ----
    for (int e = lane; e < 120; e += 64) {             // pads [200,248) x 10
        int row = e / 12, seg = e - row * 12;
        *(s16x4*)(h2s + row * ROW2 + 200 + seg * 4) = (s16x4){0, 0, 0, 0};
    }
#pragma unroll
    for (int nt = 0; nt < 2; ++nt) {
        int o = nt * 16 + lm;
        if (o < 20) {
            float bias = b2[o];
#pragma unroll
            for (int mt = 0; mt < 7; ++mt) {
#pragma unroll
                for (int r = 0; r < 4; ++r) {
                    int pos = mt * 16 + quad * 4 + r;
                    if (pos < 100) {
                        int y2 = pos / 10, x2 = pos - 10 * y2;
                        h2s[y2 * ROW2 + x2 * 20 + o] = f2bf(fmaxf(acc[mt][nt][r] + bias, 0.f));
                    }
                }
            }
        }
    }
    wave_lds_fence();

    // ---- phase 5: conv3 MFMA  M=48(36), N=32(20), K=640(500) ----
    // Fully unrolled 20 steps; distance-1 prefetch in NAMED vars.
    int abase3[3];
#pragma unroll
    for (int mt = 0; mt < 3; ++mt) {
        int m = mt * 16 + lm;
        if (m > 35) m = 35;
        int oy = m / 6, ox = m - 6 * oy;
        abase3[mt] = oy * ROW2 + ox * 20 + quad * 8;
    }
    f32x4 acc3[3][2] = {};
    {
        const unsigned short* wptr = wbuf3 + lane * 8;
        s16x8 wc0 = *(const s16x8*)(wptr);
        s16x8 wc1 = *(const s16x8*)(wptr + 512);
#pragma unroll
        for (int it = 0; it < 20; ++it) {
            s16x8 wn0 = *(const s16x8*)(wptr + (it + 1) * 1024);   // it=19 -> wband
            s16x8 wn1 = *(const s16x8*)(wptr + (it + 1) * 1024 + 512);
            const unsigned short* sbi = h2s + (it >> 2) * ROW2 + (it & 3) * 32;
            s16x8 af[3];
#pragma unroll
            for (int mt = 0; mt < 3; ++mt) {
                const unsigned short* p = sbi + abase3[mt];
                af[mt] = cat8(*(const s16x4*)(p), *(const s16x4*)(p + 4));
            }
#pragma unroll
            for (int mt = 0; mt < 3; ++mt) {
                acc3[mt][0] = __builtin_amdgcn_mfma_f32_16x16x32_bf16(af[mt], wc0, acc3[mt][0], 0, 0, 0);
                acc3[mt][1] = __builtin_amdgcn_mfma_f32_16x16x32_bf16(af[mt], wc1, acc3[mt][1], 0, 0, 0);
            }
            wc0 = wn0; wc1 = wn1;
        }
    }
    wave_lds_fence();   // h2s consumed; region becomes h3s

    // ---- phase 6: conv3 epilogue -> linear h3s[o*36+pos] (fp32, relu) ----
#pragma unroll
    for (int nt = 0; nt < 2; ++nt) {
        int o = nt * 16 + lm;
        if (o < 20) {
            float b3v = b3[o];
#pragma unroll
            for (int mt = 0; mt < 3; ++mt) {
#pragma unroll
                for (int r = 0; r < 4; ++r) {
                    int pos = mt * 16 + quad * 4 + r;
                    if (pos < 36)
                        h3s[o * 36 + pos] = fmaxf(acc3[mt][nt][r] + b3v, 0.f);
                }
            }
        }
    }
    wave_lds_fence();

    // ---- phase 7: fc — coalesced global wf, lane l handles k=l+64s ----
    float part[10];
#pragma unroll
    for (int n = 0; n < 10; ++n) part[n] = 0.f;
#pragma unroll 1
    for (int s = 0; s < 12; ++s) {
        int k = s * 64 + lane;
        if (k < 720) {
            float v = h3s[k];
#pragma unroll
            for (int n = 0; n < 10; ++n)
                part[n] = fmaf(v, wf[n * 720 + k], part[n]);
        }
    }
#pragma unroll
    for (int n = 0; n < 10; ++n) {
#pragma unroll
        for (int off = 32; off >= 1; off >>= 1)
            part[n] += __shfl_xor(part[n], off, 64);
    }
    if (lane == 0) {
        float* op = out + (size_t)b * 10;
#pragma unroll
        for (int n = 0; n < 10; ++n) op[n] = part[n] + bf[n];
    }
}

extern "C" void kernel_launch(void* const* d_in, const int* in_sizes, int n_in,
                              void* d_out, int out_size, void* d_ws, size_t ws_size,
                              hipStream_t stream) {
    (void)n_in; (void)out_size; (void)ws_size;
    const float* x  = (const float*)d_in[0];
    const float* w1 = (const float*)d_in[1];
    const float* b1 = (const float*)d_in[2];
    const float* w2 = (const float*)d_in[3];
    const float* b2 = (const float*)d_in[4];
    const float* w3 = (const float*)d_in[5];
    const float* b3 = (const float*)d_in[6];
    const float* wf = (const float*)d_in[7];
    const float* bf = (const float*)d_in[8];
    float* out = (float*)d_out;

    const int B = in_sizes[0] / 784;                   // 4096

    unsigned short* wbuf = (unsigned short*)d_ws;      // 116736 bf16 = 228 KB

    wprep_k<<<456, 256, 0, stream>>>(w1, w2, w3, wbuf);
    fused_k<<<B, 64, 0, stream>>>(x, b1, wbuf, wbuf + 40960, wbuf + 61440,
                                  b2, b3, wf, bf, out);
}